// Round 2
// baseline (1326.621 us; speedup 1.0000x reference)
//
#include <hip/hip_runtime.h>

// ---------------------------------------------------------------------------
// NodeNetwork: agg(sum over deg=16) -> concat(3x128) -> MLP(384-256-256-128)
//              -> row L2 normalize.  N=500000 rows.
// R2 strategy: SPLIT the 4.1GB message stream (pure streaming reduce kernel,
// saturates HBM) from the MLP kernel (reads bf16 agg + feat/glob, MFMA).
// Cost: +256MB agg round-trip; benefit: no bursty phase structure on the
// dominant stream.
// ---------------------------------------------------------------------------

typedef short short8   __attribute__((ext_vector_type(8)));
typedef short short4_t __attribute__((ext_vector_type(4)));
typedef float f32x4    __attribute__((ext_vector_type(4)));

#define SWZ(row, off) ((off) ^ (((row) & 7) << 4))

__device__ __forceinline__ unsigned short f2bf(float f) {
    unsigned int u = __float_as_uint(f);
    u += 0x7fffu + ((u >> 16) & 1u);   // round-to-nearest-even
    return (unsigned short)(u >> 16);
}

// ---------------------------------------------------------------------------
// Weight prep: cast fp32->bf16, pack into per-lane MFMA B-fragment order:
//   pw[((tn*KS + ks)*64 + lane)*8 + j] = bf16( W[k][n] )
//   n = tn*16 + (lane&15), k = ks*32 + (lane>>4)*8 + j
// ---------------------------------------------------------------------------
__global__ void prep_weights(const float* __restrict__ W1,
                             const float* __restrict__ W2,
                             const float* __restrict__ W3,
                             short* __restrict__ pw1,
                             short* __restrict__ pw2,
                             short* __restrict__ pw3) {
    int idx = blockIdx.x * 256 + threadIdx.x;
    if (idx < 98304) {                       // W1 [384][256]
        int j = idx & 7, l = (idx >> 3) & 63, g = idx >> 9;
        int ks = g % 12, tn = g / 12;
        int n = tn * 16 + (l & 15);
        int k = ks * 32 + ((l >> 4) << 3) + j;
        pw1[idx] = (short)f2bf(W1[k * 256 + n]);
    } else if (idx < 98304 + 65536) {        // W2 [256][256]
        int e = idx - 98304;
        int j = e & 7, l = (e >> 3) & 63, g = e >> 9;
        int ks = g & 7, tn = g >> 3;
        int n = tn * 16 + (l & 15);
        int k = ks * 32 + ((l >> 4) << 3) + j;
        pw2[e] = (short)f2bf(W2[k * 256 + n]);
    } else if (idx < 98304 + 65536 + 32768) { // W3 [256][128]
        int e = idx - 98304 - 65536;
        int j = e & 7, l = (e >> 3) & 63, g = e >> 9;
        int ks = g & 7, tn = g >> 3;
        int n = tn * 16 + (l & 15);
        int k = ks * 32 + ((l >> 4) << 3) + j;
        pw3[e] = (short)f2bf(W3[k * 128 + n]);
    }
}

// ---------------------------------------------------------------------------
// Kernel A: streaming deg-16 reduction. One f32x4 column-quarter of one row
// per thread: 16 independent 16B loads (512B stride), fp32 sum, bf16x4 store.
// No LDS, no barriers — pure HBM stream.
// ---------------------------------------------------------------------------
__global__ __launch_bounds__(256) void agg_kernel(
    const float* __restrict__ msg, short* __restrict__ agg, int n_rows)
{
    long long t = (long long)blockIdx.x * 256 + threadIdx.x;
    long long row = t >> 5;
    int f4 = (int)(t & 31);
    if (row >= n_rows) return;
    const f32x4* mp = (const f32x4*)msg + row * 512 + f4;
    f32x4 s = {0.f, 0.f, 0.f, 0.f};
    #pragma unroll
    for (int d = 0; d < 16; ++d) s += mp[d * 32];
    short4_t s4;
    s4[0] = (short)f2bf(s[0]); s4[1] = (short)f2bf(s[1]);
    s4[2] = (short)f2bf(s[2]); s4[3] = (short)f2bf(s[3]);
    *(short4_t*)(agg + row * 128 + f4 * 4) = s4;
}

// ---------------------------------------------------------------------------
// Kernel B: MLP. 32 rows/block, 256 threads (4 waves).
// All global loads issued at kernel entry (agg 8KB, feat+glob 32KB in regs).
// LDS 32KB: regA 16KB (p1 buf -> h1 -> out), regB 16KB (p0 buf | p2 buf -> h2).
// 6 barriers total. XOR swizzle ((row&7)<<4) on all tiles.
// ---------------------------------------------------------------------------
__global__ __launch_bounds__(256, 4) void node_net(
    const short* __restrict__ aggb,
    const float* __restrict__ feat,
    const float* __restrict__ glob,
    const float* __restrict__ b1v,
    const float* __restrict__ b2v,
    const float* __restrict__ b3v,
    const short* __restrict__ pw1,
    const short* __restrict__ pw2,
    const short* __restrict__ pw3,
    float* __restrict__ out,
    int n_rows)
{
    __shared__ char lds[32768];
    char* regA = lds;            // 16KB
    char* regB = lds + 16384;    // 16KB

    const int tid  = threadIdx.x;
    const int lane = tid & 63;
    const int w    = tid >> 6;
    const int lr   = lane & 15;
    const int lk   = lane >> 4;
    const long long r0 = (long long)blockIdx.x * 32;

    const f32x4 zero4 = {0.f, 0.f, 0.f, 0.f};

    // ---- issue ALL global loads now: feat/glob into regs ----
    f32x4 fr[4], gr[4];
    #pragma unroll
    for (int q = 0; q < 4; ++q) {
        int r = (tid >> 5) + q * 8;
        long long row = r0 + r;
        fr[q] = zero4; gr[q] = zero4;
        if (row < n_rows) {
            fr[q] = ((const f32x4*)feat)[row * 32 + (tid & 31)];
            gr[q] = ((const f32x4*)glob)[row * 32 + (tid & 31)];
        }
    }

    // ---- stage agg (bf16) -> regB[0:8K] ----
    #pragma unroll
    for (int pass = 0; pass < 2; ++pass) {
        int r = tid >> 3;
        int c = (tid & 7) + 8 * pass;
        long long row = r0 + r;
        short8 v = {0, 0, 0, 0, 0, 0, 0, 0};
        if (row < n_rows) v = *(const short8*)(aggb + row * 128 + c * 8);
        *(short8*)(regB + SWZ(r, r * 256 + c * 16)) = v;
    }
    __syncthreads();                                   // sync1

    // ---- stage feat regs -> regA[0:8K] (consumed after sync2) ----
    #pragma unroll
    for (int q = 0; q < 4; ++q) {
        int r = (tid >> 5) + q * 8;
        short4_t s4;
        s4[0] = (short)f2bf(fr[q][0]); s4[1] = (short)f2bf(fr[q][1]);
        s4[2] = (short)f2bf(fr[q][2]); s4[3] = (short)f2bf(fr[q][3]);
        *(short4_t*)(regA + SWZ(r, r * 256 + (tid & 31) * 8)) = s4;
    }

    f32x4 acc1[2][4];
    #pragma unroll
    for (int ri = 0; ri < 2; ++ri)
        #pragma unroll
        for (int ci = 0; ci < 4; ++ci) acc1[ri][ci] = zero4;

    // ---- GEMM1 part 0 (agg), ks = 0..3, reads regB[0:8K] ----
    #pragma unroll
    for (int s = 0; s < 4; ++s) {
        short8 a[2], b[4];
        #pragma unroll
        for (int ri = 0; ri < 2; ++ri) {
            int row = ri * 16 + lr;
            a[ri] = *(const short8*)(regB + SWZ(row, row * 256 + s * 64 + lk * 16));
        }
        #pragma unroll
        for (int ci = 0; ci < 4; ++ci) {
            int tn = w * 4 + ci;
            b[ci] = *(const short8*)(pw1 + (((tn * 12 + s) * 64 + lane) << 3));
        }
        #pragma unroll
        for (int ri = 0; ri < 2; ++ri)
            #pragma unroll
            for (int ci = 0; ci < 4; ++ci)
                acc1[ri][ci] = __builtin_amdgcn_mfma_f32_16x16x32_bf16(
                    a[ri], b[ci], acc1[ri][ci], 0, 0, 0);
    }
    __syncthreads();                                   // sync2

    // ---- stage glob regs -> regB[8K:16K] (consumed after sync3) ----
    #pragma unroll
    for (int q = 0; q < 4; ++q) {
        int r = (tid >> 5) + q * 8;
        short4_t s4;
        s4[0] = (short)f2bf(gr[q][0]); s4[1] = (short)f2bf(gr[q][1]);
        s4[2] = (short)f2bf(gr[q][2]); s4[3] = (short)f2bf(gr[q][3]);
        *(short4_t*)(regB + 8192 + SWZ(r, r * 256 + (tid & 31) * 8)) = s4;
    }

    // ---- GEMM1 part 1 (feat), ks = 4..7, reads regA[0:8K] ----
    #pragma unroll
    for (int s = 0; s < 4; ++s) {
        short8 a[2], b[4];
        #pragma unroll
        for (int ri = 0; ri < 2; ++ri) {
            int row = ri * 16 + lr;
            a[ri] = *(const short8*)(regA + SWZ(row, row * 256 + s * 64 + lk * 16));
        }
        #pragma unroll
        for (int ci = 0; ci < 4; ++ci) {
            int tn = w * 4 + ci;
            b[ci] = *(const short8*)(pw1 + (((tn * 12 + 4 + s) * 64 + lane) << 3));
        }
        #pragma unroll
        for (int ri = 0; ri < 2; ++ri)
            #pragma unroll
            for (int ci = 0; ci < 4; ++ci)
                acc1[ri][ci] = __builtin_amdgcn_mfma_f32_16x16x32_bf16(
                    a[ri], b[ci], acc1[ri][ci], 0, 0, 0);
    }
    __syncthreads();                                   // sync3

    // ---- GEMM1 part 2 (glob), ks = 8..11, reads regB[8K:16K] ----
    #pragma unroll
    for (int s = 0; s < 4; ++s) {
        short8 a[2], b[4];
        #pragma unroll
        for (int ri = 0; ri < 2; ++ri) {
            int row = ri * 16 + lr;
            a[ri] = *(const short8*)(regB + 8192 + SWZ(row, row * 256 + s * 64 + lk * 16));
        }
        #pragma unroll
        for (int ci = 0; ci < 4; ++ci) {
            int tn = w * 4 + ci;
            b[ci] = *(const short8*)(pw1 + (((tn * 12 + 8 + s) * 64 + lane) << 3));
        }
        #pragma unroll
        for (int ri = 0; ri < 2; ++ri)
            #pragma unroll
            for (int ci = 0; ci < 4; ++ci)
                acc1[ri][ci] = __builtin_amdgcn_mfma_f32_16x16x32_bf16(
                    a[ri], b[ci], acc1[ri][ci], 0, 0, 0);
    }

    // ---- epilogue 1: +b1, ReLU, bf16 -> h1 in regA (p1 data dead) ----
    #pragma unroll
    for (int ci = 0; ci < 4; ++ci) {
        int col = w * 64 + ci * 16 + lr;
        float bias = b1v[col];
        #pragma unroll
        for (int ri = 0; ri < 2; ++ri)
            #pragma unroll
            for (int i = 0; i < 4; ++i) {
                int row = ri * 16 + lk * 4 + i;
                float v = fmaxf(acc1[ri][ci][i] + bias, 0.f);
                *(short*)(regA + SWZ(row, row * 512 + col * 2)) = (short)f2bf(v);
            }
    }
    __syncthreads();                                   // sync4

    // ---- GEMM2: h1 @ W2 (reads regA) ----
    f32x4 acc2[2][4];
    #pragma unroll
    for (int ri = 0; ri < 2; ++ri)
        #pragma unroll
        for (int ci = 0; ci < 4; ++ci) acc2[ri][ci] = zero4;

    #pragma unroll
    for (int s = 0; s < 8; ++s) {
        short8 a[2], b[4];
        #pragma unroll
        for (int ri = 0; ri < 2; ++ri) {
            int row = ri * 16 + lr;
            a[ri] = *(const short8*)(regA + SWZ(row, row * 512 + s * 64 + lk * 16));
        }
        #pragma unroll
        for (int ci = 0; ci < 4; ++ci) {
            int tn = w * 4 + ci;
            b[ci] = *(const short8*)(pw2 + (((tn * 8 + s) * 64 + lane) << 3));
        }
        #pragma unroll
        for (int ri = 0; ri < 2; ++ri)
            #pragma unroll
            for (int ci = 0; ci < 4; ++ci)
                acc2[ri][ci] = __builtin_amdgcn_mfma_f32_16x16x32_bf16(
                    a[ri], b[ci], acc2[ri][ci], 0, 0, 0);
    }

    // ---- epilogue 2: +b2, ReLU, bf16 -> h2 in regB ----
    #pragma unroll
    for (int ci = 0; ci < 4; ++ci) {
        int col = w * 64 + ci * 16 + lr;
        float bias = b2v[col];
        #pragma unroll
        for (int ri = 0; ri < 2; ++ri)
            #pragma unroll
            for (int i = 0; i < 4; ++i) {
                int row = ri * 16 + lk * 4 + i;
                float v = fmaxf(acc2[ri][ci][i] + bias, 0.f);
                *(short*)(regB + SWZ(row, row * 512 + col * 2)) = (short)f2bf(v);
            }
    }
    __syncthreads();                                   // sync5

    // ---- GEMM3: h2 @ W3 (reads regB) ----
    f32x4 acc3[2][2];
    #pragma unroll
    for (int ri = 0; ri < 2; ++ri)
        #pragma unroll
        for (int ci = 0; ci < 2; ++ci) acc3[ri][ci] = zero4;

    #pragma unroll
    for (int s = 0; s < 8; ++s) {
        short8 a[2], b[2];
        #pragma unroll
        for (int ri = 0; ri < 2; ++ri) {
            int row = ri * 16 + lr;
            a[ri] = *(const short8*)(regB + SWZ(row, row * 512 + s * 64 + lk * 16));
        }
        #pragma unroll
        for (int ci = 0; ci < 2; ++ci) {
            int tn = w * 2 + ci;
            b[ci] = *(const short8*)(pw3 + (((tn * 8 + s) * 64 + lane) << 3));
        }
        #pragma unroll
        for (int ri = 0; ri < 2; ++ri)
            #pragma unroll
            for (int ci = 0; ci < 2; ++ci)
                acc3[ri][ci] = __builtin_amdgcn_mfma_f32_16x16x32_bf16(
                    a[ri], b[ci], acc3[ri][ci], 0, 0, 0);
    }

    // ---- epilogue 3: +b3, f32 -> out tile in regA ----
    #pragma unroll
    for (int ci = 0; ci < 2; ++ci) {
        int col = w * 32 + ci * 16 + lr;
        float bias = b3v[col];
        #pragma unroll
        for (int ri = 0; ri < 2; ++ri)
            #pragma unroll
            for (int i = 0; i < 4; ++i) {
                int row = ri * 16 + lk * 4 + i;
                float v = acc3[ri][ci][i] + bias;
                *(float*)(regA + SWZ(row, row * 512 + col * 4)) = v;
            }
    }
    __syncthreads();                                   // sync6

    // ---- row-wise L2 normalize + coalesced store ----
    #pragma unroll
    for (int pass = 0; pass < 4; ++pass) {
        const int r  = (tid >> 5) + pass * 8;
        const int fl = tid & 31;
        f32x4 v = *(const f32x4*)(regA + SWZ(r, r * 512 + fl * 16));
        float ss = v[0]*v[0] + v[1]*v[1] + v[2]*v[2] + v[3]*v[3];
        ss += __shfl_xor(ss, 1, 32);
        ss += __shfl_xor(ss, 2, 32);
        ss += __shfl_xor(ss, 4, 32);
        ss += __shfl_xor(ss, 8, 32);
        ss += __shfl_xor(ss, 16, 32);
        float inv = 1.f / (sqrtf(ss) + 1e-8f);
        long long row = r0 + r;
        if (row < n_rows) {
            f32x4 o = v * inv;
            ((f32x4*)out)[row * 32 + fl] = o;
        }
    }
}

// ---------------------------------------------------------------------------
extern "C" void kernel_launch(void* const* d_in, const int* in_sizes, int n_in,
                              void* d_out, int out_size, void* d_ws, size_t ws_size,
                              hipStream_t stream) {
    const float* msg  = (const float*)d_in[0];
    const float* feat = (const float*)d_in[1];
    const float* glob = (const float*)d_in[2];
    const float* W1   = (const float*)d_in[3];
    const float* b1   = (const float*)d_in[4];
    const float* W2   = (const float*)d_in[5];
    const float* b2   = (const float*)d_in[6];
    const float* W3   = (const float*)d_in[7];
    const float* b3   = (const float*)d_in[8];
    float* out = (float*)d_out;

    const int n_rows = in_sizes[1] / 128;   // features is [N,128]

    short* pw1  = (short*)d_ws;             // 98304 bf16
    short* pw2  = pw1 + 98304;              // 65536 bf16
    short* pw3  = pw2 + 65536;              // 32768 bf16
    short* aggb = pw3 + 32768;              // N*128 bf16 (128 MB @ N=500k)

    hipLaunchKernelGGL(prep_weights, dim3(768), dim3(256), 0, stream,
                       W1, W2, W3, pw1, pw2, pw3);

    const long long athreads = (long long)n_rows * 32;
    const int ablocks = (int)((athreads + 255) / 256);
    hipLaunchKernelGGL(agg_kernel, dim3(ablocks), dim3(256), 0, stream,
                       msg, aggb, n_rows);

    const int nblocks = (n_rows + 31) / 32;
    hipLaunchKernelGGL(node_net, dim3(nblocks), dim3(256), 0, stream,
                       aggb, feat, glob, b1, b2, b3, pw1, pw2, pw3, out, n_rows);
}

// Round 3
// 1275.573 us; speedup vs baseline: 1.0400x; 1.0400x over previous
//
#include <hip/hip_runtime.h>

// ---------------------------------------------------------------------------
// NodeNetwork: agg(sum over deg=16) -> concat(3x128) -> MLP(384-256-256-128)
//              -> row L2 normalize.  N=500000 rows.
// R3: agg_kernel rewritten for 1KB wave-contiguous nontemporal loads
// (A/B vs R2's dual-512B-segment wave loads). node_net unchanged from R2.
// ---------------------------------------------------------------------------

typedef short short8   __attribute__((ext_vector_type(8)));
typedef short short4_t __attribute__((ext_vector_type(4)));
typedef float f32x4    __attribute__((ext_vector_type(4)));

#define SWZ(row, off) ((off) ^ (((row) & 7) << 4))

__device__ __forceinline__ unsigned short f2bf(float f) {
    unsigned int u = __float_as_uint(f);
    u += 0x7fffu + ((u >> 16) & 1u);   // round-to-nearest-even
    return (unsigned short)(u >> 16);
}

// ---------------------------------------------------------------------------
// Weight prep: cast fp32->bf16, pack into per-lane MFMA B-fragment order:
//   pw[((tn*KS + ks)*64 + lane)*8 + j] = bf16( W[k][n] )
//   n = tn*16 + (lane&15), k = ks*32 + (lane>>4)*8 + j
// ---------------------------------------------------------------------------
__global__ void prep_weights(const float* __restrict__ W1,
                             const float* __restrict__ W2,
                             const float* __restrict__ W3,
                             short* __restrict__ pw1,
                             short* __restrict__ pw2,
                             short* __restrict__ pw3) {
    int idx = blockIdx.x * 256 + threadIdx.x;
    if (idx < 98304) {                       // W1 [384][256]
        int j = idx & 7, l = (idx >> 3) & 63, g = idx >> 9;
        int ks = g % 12, tn = g / 12;
        int n = tn * 16 + (l & 15);
        int k = ks * 32 + ((l >> 4) << 3) + j;
        pw1[idx] = (short)f2bf(W1[k * 256 + n]);
    } else if (idx < 98304 + 65536) {        // W2 [256][256]
        int e = idx - 98304;
        int j = e & 7, l = (e >> 3) & 63, g = e >> 9;
        int ks = g & 7, tn = g >> 3;
        int n = tn * 16 + (l & 15);
        int k = ks * 32 + ((l >> 4) << 3) + j;
        pw2[e] = (short)f2bf(W2[k * 256 + n]);
    } else if (idx < 98304 + 65536 + 32768) { // W3 [256][128]
        int e = idx - 98304 - 65536;
        int j = e & 7, l = (e >> 3) & 63, g = e >> 9;
        int ks = g & 7, tn = g >> 3;
        int n = tn * 16 + (l & 15);
        int k = ks * 32 + ((l >> 4) << 3) + j;
        pw3[e] = (short)f2bf(W3[k * 128 + n]);
    }
}

// ---------------------------------------------------------------------------
// Kernel A (R3): streaming deg-16 reduction with PERFECT wave coalescing.
// Block = 256 threads = 4 waves; block handles 8 rows (64KB contiguous).
// Wave w owns row pair (8*blk + 2w, +1): 16 loads, each 1KB wave-contiguous
// nontemporal dwordx4. Lane l accumulates d in {2i + (l>>5)}; one
// shfl_xor(32) merges the complementary d-halves; 512B contiguous bf16 store.
// ---------------------------------------------------------------------------
__global__ __launch_bounds__(256) void agg_kernel(
    const float* __restrict__ msg, short* __restrict__ agg, int n_rows)
{
    const int w = threadIdx.x >> 6;
    const int l = threadIdx.x & 63;
    const long long pb = (long long)blockIdx.x * 8 + 2 * w;  // pair base row
    if (pb >= n_rows) return;

    const f32x4* base = (const f32x4*)((const char*)msg + pb * 8192);
    // element index for (load i, lane l): i*64 + l  (i.e. byte i*1024 + l*16)
    f32x4 tA[8], tB[8];
    const bool okB = (pb + 1) < n_rows;
    #pragma unroll
    for (int i = 0; i < 8; ++i) tA[i] = __builtin_nontemporal_load(base + i * 64 + l);
    if (okB) {
        #pragma unroll
        for (int i = 0; i < 8; ++i) tB[i] = __builtin_nontemporal_load(base + (8 + i) * 64 + l);
    } else {
        #pragma unroll
        for (int i = 0; i < 8; ++i) tB[i] = (f32x4){0.f, 0.f, 0.f, 0.f};
    }
    // tree-sum the 8 partials per row
    f32x4 sA = ((tA[0] + tA[1]) + (tA[2] + tA[3])) + ((tA[4] + tA[5]) + (tA[6] + tA[7]));
    f32x4 sB = ((tB[0] + tB[1]) + (tB[2] + tB[3])) + ((tB[4] + tB[5]) + (tB[6] + tB[7]));
    // merge complementary d-halves held by lane l^32
    #pragma unroll
    for (int c = 0; c < 4; ++c) {
        sA[c] += __shfl_xor(sA[c], 32);
        sB[c] += __shfl_xor(sB[c], 32);
    }
    // lane l stores row pb + (l>>5), f4 = l&31 : 8B bf16x4, 512B/wave contig
    f32x4 s = (l < 32) ? sA : sB;
    short4_t s4;
    s4[0] = (short)f2bf(s[0]); s4[1] = (short)f2bf(s[1]);
    s4[2] = (short)f2bf(s[2]); s4[3] = (short)f2bf(s[3]);
    const long long orow = pb + (l >> 5);
    if (orow < n_rows)
        *(short4_t*)(agg + orow * 128 + (l & 31) * 4) = s4;
}

// ---------------------------------------------------------------------------
// Kernel B: MLP — UNCHANGED from R2 (isolate the agg access-pattern variable).
// 32 rows/block, 256 threads (4 waves). LDS 32KB.
// ---------------------------------------------------------------------------
__global__ __launch_bounds__(256, 4) void node_net(
    const short* __restrict__ aggb,
    const float* __restrict__ feat,
    const float* __restrict__ glob,
    const float* __restrict__ b1v,
    const float* __restrict__ b2v,
    const float* __restrict__ b3v,
    const short* __restrict__ pw1,
    const short* __restrict__ pw2,
    const short* __restrict__ pw3,
    float* __restrict__ out,
    int n_rows)
{
    __shared__ char lds[32768];
    char* regA = lds;            // 16KB
    char* regB = lds + 16384;    // 16KB

    const int tid  = threadIdx.x;
    const int lane = tid & 63;
    const int w    = tid >> 6;
    const int lr   = lane & 15;
    const int lk   = lane >> 4;
    const long long r0 = (long long)blockIdx.x * 32;

    const f32x4 zero4 = {0.f, 0.f, 0.f, 0.f};

    // ---- issue ALL global loads now: feat/glob into regs ----
    f32x4 fr[4], gr[4];
    #pragma unroll
    for (int q = 0; q < 4; ++q) {
        int r = (tid >> 5) + q * 8;
        long long row = r0 + r;
        fr[q] = zero4; gr[q] = zero4;
        if (row < n_rows) {
            fr[q] = ((const f32x4*)feat)[row * 32 + (tid & 31)];
            gr[q] = ((const f32x4*)glob)[row * 32 + (tid & 31)];
        }
    }

    // ---- stage agg (bf16) -> regB[0:8K] ----
    #pragma unroll
    for (int pass = 0; pass < 2; ++pass) {
        int r = tid >> 3;
        int c = (tid & 7) + 8 * pass;
        long long row = r0 + r;
        short8 v = {0, 0, 0, 0, 0, 0, 0, 0};
        if (row < n_rows) v = *(const short8*)(aggb + row * 128 + c * 8);
        *(short8*)(regB + SWZ(r, r * 256 + c * 16)) = v;
    }
    __syncthreads();                                   // sync1

    // ---- stage feat regs -> regA[0:8K] (consumed after sync2) ----
    #pragma unroll
    for (int q = 0; q < 4; ++q) {
        int r = (tid >> 5) + q * 8;
        short4_t s4;
        s4[0] = (short)f2bf(fr[q][0]); s4[1] = (short)f2bf(fr[q][1]);
        s4[2] = (short)f2bf(fr[q][2]); s4[3] = (short)f2bf(fr[q][3]);
        *(short4_t*)(regA + SWZ(r, r * 256 + (tid & 31) * 8)) = s4;
    }

    f32x4 acc1[2][4];
    #pragma unroll
    for (int ri = 0; ri < 2; ++ri)
        #pragma unroll
        for (int ci = 0; ci < 4; ++ci) acc1[ri][ci] = zero4;

    // ---- GEMM1 part 0 (agg), ks = 0..3, reads regB[0:8K] ----
    #pragma unroll
    for (int s = 0; s < 4; ++s) {
        short8 a[2], b[4];
        #pragma unroll
        for (int ri = 0; ri < 2; ++ri) {
            int row = ri * 16 + lr;
            a[ri] = *(const short8*)(regB + SWZ(row, row * 256 + s * 64 + lk * 16));
        }
        #pragma unroll
        for (int ci = 0; ci < 4; ++ci) {
            int tn = w * 4 + ci;
            b[ci] = *(const short8*)(pw1 + (((tn * 12 + s) * 64 + lane) << 3));
        }
        #pragma unroll
        for (int ri = 0; ri < 2; ++ri)
            #pragma unroll
            for (int ci = 0; ci < 4; ++ci)
                acc1[ri][ci] = __builtin_amdgcn_mfma_f32_16x16x32_bf16(
                    a[ri], b[ci], acc1[ri][ci], 0, 0, 0);
    }
    __syncthreads();                                   // sync2

    // ---- stage glob regs -> regB[8K:16K] (consumed after sync3) ----
    #pragma unroll
    for (int q = 0; q < 4; ++q) {
        int r = (tid >> 5) + q * 8;
        short4_t s4;
        s4[0] = (short)f2bf(gr[q][0]); s4[1] = (short)f2bf(gr[q][1]);
        s4[2] = (short)f2bf(gr[q][2]); s4[3] = (short)f2bf(gr[q][3]);
        *(short4_t*)(regB + 8192 + SWZ(r, r * 256 + (tid & 31) * 8)) = s4;
    }

    // ---- GEMM1 part 1 (feat), ks = 4..7, reads regA[0:8K] ----
    #pragma unroll
    for (int s = 0; s < 4; ++s) {
        short8 a[2], b[4];
        #pragma unroll
        for (int ri = 0; ri < 2; ++ri) {
            int row = ri * 16 + lr;
            a[ri] = *(const short8*)(regA + SWZ(row, row * 256 + s * 64 + lk * 16));
        }
        #pragma unroll
        for (int ci = 0; ci < 4; ++ci) {
            int tn = w * 4 + ci;
            b[ci] = *(const short8*)(pw1 + (((tn * 12 + 4 + s) * 64 + lane) << 3));
        }
        #pragma unroll
        for (int ri = 0; ri < 2; ++ri)
            #pragma unroll
            for (int ci = 0; ci < 4; ++ci)
                acc1[ri][ci] = __builtin_amdgcn_mfma_f32_16x16x32_bf16(
                    a[ri], b[ci], acc1[ri][ci], 0, 0, 0);
    }
    __syncthreads();                                   // sync3

    // ---- GEMM1 part 2 (glob), ks = 8..11, reads regB[8K:16K] ----
    #pragma unroll
    for (int s = 0; s < 4; ++s) {
        short8 a[2], b[4];
        #pragma unroll
        for (int ri = 0; ri < 2; ++ri) {
            int row = ri * 16 + lr;
            a[ri] = *(const short8*)(regB + 8192 + SWZ(row, row * 256 + s * 64 + lk * 16));
        }
        #pragma unroll
        for (int ci = 0; ci < 4; ++ci) {
            int tn = w * 4 + ci;
            b[ci] = *(const short8*)(pw1 + (((tn * 12 + 8 + s) * 64 + lane) << 3));
        }
        #pragma unroll
        for (int ri = 0; ri < 2; ++ri)
            #pragma unroll
            for (int ci = 0; ci < 4; ++ci)
                acc1[ri][ci] = __builtin_amdgcn_mfma_f32_16x16x32_bf16(
                    a[ri], b[ci], acc1[ri][ci], 0, 0, 0);
    }

    // ---- epilogue 1: +b1, ReLU, bf16 -> h1 in regA (p1 data dead) ----
    #pragma unroll
    for (int ci = 0; ci < 4; ++ci) {
        int col = w * 64 + ci * 16 + lr;
        float bias = b1v[col];
        #pragma unroll
        for (int ri = 0; ri < 2; ++ri)
            #pragma unroll
            for (int i = 0; i < 4; ++i) {
                int row = ri * 16 + lk * 4 + i;
                float v = fmaxf(acc1[ri][ci][i] + bias, 0.f);
                *(short*)(regA + SWZ(row, row * 512 + col * 2)) = (short)f2bf(v);
            }
    }
    __syncthreads();                                   // sync4

    // ---- GEMM2: h1 @ W2 (reads regA) ----
    f32x4 acc2[2][4];
    #pragma unroll
    for (int ri = 0; ri < 2; ++ri)
        #pragma unroll
        for (int ci = 0; ci < 4; ++ci) acc2[ri][ci] = zero4;

    #pragma unroll
    for (int s = 0; s < 8; ++s) {
        short8 a[2], b[4];
        #pragma unroll
        for (int ri = 0; ri < 2; ++ri) {
            int row = ri * 16 + lr;
            a[ri] = *(const short8*)(regA + SWZ(row, row * 512 + s * 64 + lk * 16));
        }
        #pragma unroll
        for (int ci = 0; ci < 4; ++ci) {
            int tn = w * 4 + ci;
            b[ci] = *(const short8*)(pw2 + (((tn * 8 + s) * 64 + lane) << 3));
        }
        #pragma unroll
        for (int ri = 0; ri < 2; ++ri)
            #pragma unroll
            for (int ci = 0; ci < 4; ++ci)
                acc2[ri][ci] = __builtin_amdgcn_mfma_f32_16x16x32_bf16(
                    a[ri], b[ci], acc2[ri][ci], 0, 0, 0);
    }

    // ---- epilogue 2: +b2, ReLU, bf16 -> h2 in regB ----
    #pragma unroll
    for (int ci = 0; ci < 4; ++ci) {
        int col = w * 64 + ci * 16 + lr;
        float bias = b2v[col];
        #pragma unroll
        for (int ri = 0; ri < 2; ++ri)
            #pragma unroll
            for (int i = 0; i < 4; ++i) {
                int row = ri * 16 + lk * 4 + i;
                float v = fmaxf(acc2[ri][ci][i] + bias, 0.f);
                *(short*)(regB + SWZ(row, row * 512 + col * 2)) = (short)f2bf(v);
            }
    }
    __syncthreads();                                   // sync5

    // ---- GEMM3: h2 @ W3 (reads regB) ----
    f32x4 acc3[2][2];
    #pragma unroll
    for (int ri = 0; ri < 2; ++ri)
        #pragma unroll
        for (int ci = 0; ci < 2; ++ci) acc3[ri][ci] = zero4;

    #pragma unroll
    for (int s = 0; s < 8; ++s) {
        short8 a[2], b[2];
        #pragma unroll
        for (int ri = 0; ri < 2; ++ri) {
            int row = ri * 16 + lr;
            a[ri] = *(const short8*)(regB + SWZ(row, row * 512 + s * 64 + lk * 16));
        }
        #pragma unroll
        for (int ci = 0; ci < 2; ++ci) {
            int tn = w * 2 + ci;
            b[ci] = *(const short8*)(pw3 + (((tn * 8 + s) * 64 + lane) << 3));
        }
        #pragma unroll
        for (int ri = 0; ri < 2; ++ri)
            #pragma unroll
            for (int ci = 0; ci < 2; ++ci)
                acc3[ri][ci] = __builtin_amdgcn_mfma_f32_16x16x32_bf16(
                    a[ri], b[ci], acc3[ri][ci], 0, 0, 0);
    }

    // ---- epilogue 3: +b3, f32 -> out tile in regA ----
    #pragma unroll
    for (int ci = 0; ci < 2; ++ci) {
        int col = w * 32 + ci * 16 + lr;
        float bias = b3v[col];
        #pragma unroll
        for (int ri = 0; ri < 2; ++ri)
            #pragma unroll
            for (int i = 0; i < 4; ++i) {
                int row = ri * 16 + lk * 4 + i;
                float v = acc3[ri][ci][i] + bias;
                *(float*)(regA + SWZ(row, row * 512 + col * 4)) = v;
            }
    }
    __syncthreads();                                   // sync6

    // ---- row-wise L2 normalize + coalesced store ----
    #pragma unroll
    for (int pass = 0; pass < 4; ++pass) {
        const int r  = (tid >> 5) + pass * 8;
        const int fl = tid & 31;
        f32x4 v = *(const f32x4*)(regA + SWZ(r, r * 512 + fl * 16));
        float ss = v[0]*v[0] + v[1]*v[1] + v[2]*v[2] + v[3]*v[3];
        ss += __shfl_xor(ss, 1, 32);
        ss += __shfl_xor(ss, 2, 32);
        ss += __shfl_xor(ss, 4, 32);
        ss += __shfl_xor(ss, 8, 32);
        ss += __shfl_xor(ss, 16, 32);
        float inv = 1.f / (sqrtf(ss) + 1e-8f);
        long long row = r0 + r;
        if (row < n_rows) {
            f32x4 o = v * inv;
            ((f32x4*)out)[row * 32 + fl] = o;
        }
    }
}

// ---------------------------------------------------------------------------
extern "C" void kernel_launch(void* const* d_in, const int* in_sizes, int n_in,
                              void* d_out, int out_size, void* d_ws, size_t ws_size,
                              hipStream_t stream) {
    const float* msg  = (const float*)d_in[0];
    const float* feat = (const float*)d_in[1];
    const float* glob = (const float*)d_in[2];
    const float* W1   = (const float*)d_in[3];
    const float* b1   = (const float*)d_in[4];
    const float* W2   = (const float*)d_in[5];
    const float* b2   = (const float*)d_in[6];
    const float* W3   = (const float*)d_in[7];
    const float* b3   = (const float*)d_in[8];
    float* out = (float*)d_out;

    const int n_rows = in_sizes[1] / 128;   // features is [N,128]

    short* pw1  = (short*)d_ws;             // 98304 bf16
    short* pw2  = pw1 + 98304;              // 65536 bf16
    short* pw3  = pw2 + 65536;              // 32768 bf16
    short* aggb = pw3 + 32768;              // N*128 bf16 (128 MB @ N=500k)

    hipLaunchKernelGGL(prep_weights, dim3(768), dim3(256), 0, stream,
                       W1, W2, W3, pw1, pw2, pw3);

    const int ablocks = (n_rows + 7) / 8;   // 8 rows per block
    hipLaunchKernelGGL(agg_kernel, dim3(ablocks), dim3(256), 0, stream,
                       msg, aggb, n_rows);

    const int nblocks = (n_rows + 31) / 32;
    hipLaunchKernelGGL(node_net, dim3(nblocks), dim3(256), 0, stream,
                       aggb, feat, glob, b1, b2, b3, pw1, pw2, pw3, out, n_rows);
}